// Round 2
// baseline (1860.320 us; speedup 1.0000x reference)
//
#include <hip/hip_runtime.h>
#include <stdint.h>

// ---------------- problem constants ----------------
#define BB   2
#define SS   1024
#define NH   32
#define NKV  8
#define HD   128
#define DQ   4096      // NH*HD
#define DKV  1024      // NKV*HD
#define DD   6144      // DQ + 2*DKV
#define MM   2048      // B*S
#define SCALE 0.08838834764831845f   // 1/sqrt(128)

typedef __attribute__((ext_vector_type(8))) short short8;
typedef __attribute__((ext_vector_type(4))) float f4;

// ---------------- helpers ----------------
__device__ __forceinline__ float b2f(unsigned short b) {
    union { unsigned int u; float f; } v; v.u = ((unsigned int)b) << 16; return v.f;
}
__device__ __forceinline__ unsigned short f2b(float f) {
    union { float f; unsigned int u; } v; v.f = f;
    unsigned int u = v.u;
    unsigned int r = u + 0x7fffu + ((u >> 16) & 1u);
    return (unsigned short)(r >> 16);
}
__device__ __forceinline__ float fqs(float x, float s) {   // symmetric fake-quant, qp=127
    return fminf(fmaxf(rintf(x / s), -127.f), 127.f) * s;
}

typedef const unsigned int __attribute__((address_space(1)))* gas_ptr;
typedef unsigned int __attribute__((address_space(3)))* las_ptr;
__device__ __forceinline__ void gl_lds16(const void* g, void* l) {
    __builtin_amdgcn_global_load_lds((gas_ptr)(uintptr_t)g,
                                     (las_ptr)(unsigned int)(uintptr_t)l, 16, 0, 0);
}

// ---------------- dtype detector: scal[6] = 1.0 if inputs are f32 ----------------
__global__ void detect_kernel(const unsigned short* __restrict__ x, float* scal) {
    __shared__ float w[4];
    int tid = threadIdx.x;
    float m = 0.f;
    for (int i = tid; i < 65536; i += 256) m = fmaxf(m, fabsf(b2f(x[i])));
#pragma unroll
    for (int off = 32; off > 0; off >>= 1) m = fmaxf(m, __shfl_down(m, off));
    if ((tid & 63) == 0) w[tid >> 6] = m;
    __syncthreads();
    if (tid == 0) {
        float mm = fmaxf(fmaxf(w[0], w[1]), fmaxf(w[2], w[3]));
        scal[6] = (mm > 1e4f) ? 1.0f : 0.0f;
    }
}

__global__ void slope_kernel(const unsigned short* __restrict__ sp, float* scal) {
    if (threadIdx.x == 0)
        scal[7] = (scal[6] > 0.5f) ? ((const float*)sp)[0] : b2f(sp[0]);
}

// ---------------- split input (f32 or bf16) -> bf16 hi + bf16 lo ----------------
__global__ void convert_split_kernel(const unsigned short* __restrict__ src,
                                     unsigned short* __restrict__ hi,
                                     unsigned short* __restrict__ lo,
                                     const float* __restrict__ scal) {
    size_t t = (size_t)blockIdx.x * 256 + threadIdx.x;
    float v[8] __attribute__((aligned(16)));
    if (scal[6] > 0.5f) {
        const float* s = (const float*)src + t * 8;
        *(float4*)(v)     = *(const float4*)(s);
        *(float4*)(v + 4) = *(const float4*)(s + 4);
    } else {
        unsigned short u[8] __attribute__((aligned(16)));
        *(uint4*)u = *(const uint4*)(src + t * 8);
#pragma unroll
        for (int i = 0; i < 8; i++) v[i] = b2f(u[i]);
    }
    unsigned short h8[8] __attribute__((aligned(16)));
    unsigned short l8[8] __attribute__((aligned(16)));
#pragma unroll
    for (int i = 0; i < 8; i++) {
        unsigned short h = f2b(v[i]);
        h8[i] = h;
        l8[i] = f2b(v[i] - b2f(h));
    }
    *(uint4*)(hi + t * 8) = *(uint4*)h8;
    *(uint4*)(lo + t * 8) = *(uint4*)l8;
}

// ---------------- hi/lo GEMM  C[M,N] = A[M,K] * B[N,K]^T  (f32-accurate) ----------------
// NT=3: C = Ah Bh + Al Bh + Ah Bl   (MODE 0: qkv -> amax slots 0..2)
// NT=2: C = (Ah Bh + Ah Bl) * s_O   (MODE 1: out -> amax slot 5)
// 128x128 block tile, 2 waves (128 thr), per-wave 128x64 output (LDS-BW-optimal),
// BK=32, 2 LDS buffers, counted-vmcnt pipeline (stage t+2 in flight across raw barriers),
// chunk-XOR LDS swizzle (both-sides: pre-swizzled global source + swizzled ds_read),
// XCD-aware block swizzle.
template<int NT, int MODE>
__global__ __launch_bounds__(128, 1)
void gemm_hilo_kernel(const unsigned short* __restrict__ Ah,
                      const unsigned short* __restrict__ Al,
                      const unsigned short* __restrict__ Bh,
                      const unsigned short* __restrict__ Bl,
                      float* __restrict__ C,
                      int M, int N, int K,
                      float* __restrict__ scal)
{
    constexpr int PA    = 128 * 32;                  // shorts per panel
    constexpr int OAL   = PA;                        // Al (NT3 only)
    constexpr int OBH   = (NT == 3) ? 2 * PA : PA;
    constexpr int OBL   = OBH + PA;
    constexpr int BUFSH = OBL + PA;                  // shorts per buffer
    __shared__ unsigned short lds[2 * BUFSH];
    __shared__ float wred[2];

    const int tid = threadIdx.x;
    const int wave = tid >> 6, lane = tid & 63;
    const int lm = lane & 15, quad = lane >> 4;
    const int qx = quad ^ ((lm >> 1) & 3);           // read-side swizzle
    const int fo = lm * 32 + qx * 8;                 // frag offset within 16-row group

    // XCD-swizzled 1-D block decode (grid % 8 == 0 guaranteed by launch)
    const int nbn = N >> 7;
    const int nwg = (M >> 7) * nbn;
    const int bid = blockIdx.x;
    const int wg  = (bid & 7) * (nwg >> 3) + (bid >> 3);
    const int bm  = (wg / nbn) << 7;
    const int bn  = (wg % nbn) << 7;

    // staging geometry: thread stages 4 chunks/panel; pre-swizzled global column
    const int rowB = tid >> 2;                               // 0..31
    const int colO = ((tid & 3) ^ ((tid >> 3) & 3)) * 8;     // swizzled col chunk
    const size_t gA = (size_t)bm * K;
    const size_t gB = (size_t)bn * K;

    const f4 z = {0.f, 0.f, 0.f, 0.f};
    f4 acc[8][4];
#pragma unroll
    for (int i = 0; i < 8; i++)
#pragma unroll
        for (int j = 0; j < 4; j++) acc[i][j] = z;

    auto stage = [&](int bsel, int k0) {
        unsigned short* L = lds + bsel * BUFSH;
#pragma unroll
        for (int kk2 = 0; kk2 < 4; kk2++) {
            int rr = kk2 * 32 + rowB;
            size_t go = (size_t)rr * K + k0 + colO;
            int ld = (kk2 * 128 + tid) * 8;
            gl_lds16(Ah + gA + go, L + ld);
            if (NT == 3) gl_lds16(Al + gA + go, L + OAL + ld);
            gl_lds16(Bh + gB + go, L + OBH + ld);
            gl_lds16(Bl + gB + go, L + OBL + ld);
        }
    };

    auto compute = [&](int bsel) {
        const unsigned short* L = lds + bsel * BUFSH;
        short8 a_h[8], b_h[4], b_l[4];
        short8 a_l[(NT == 3) ? 8 : 1];
#pragma unroll
        for (int i = 0; i < 8; i++) {
            a_h[i] = *(const short8*)(L + i * 512 + fo);
            if (NT == 3) a_l[i] = *(const short8*)(L + OAL + i * 512 + fo);
        }
        const int wb = wave * 2048;
#pragma unroll
        for (int j = 0; j < 4; j++) {
            b_h[j] = *(const short8*)(L + OBH + wb + j * 512 + fo);
            b_l[j] = *(const short8*)(L + OBL + wb + j * 512 + fo);
        }
#pragma unroll
        for (int i = 0; i < 8; i++)
#pragma unroll
            for (int j = 0; j < 4; j++) {
                acc[i][j] = __builtin_amdgcn_mfma_f32_16x16x32_bf16(a_h[i], b_h[j], acc[i][j], 0, 0, 0);
                if (NT == 3)
                    acc[i][j] = __builtin_amdgcn_mfma_f32_16x16x32_bf16(a_l[i], b_h[j], acc[i][j], 0, 0, 0);
                acc[i][j] = __builtin_amdgcn_mfma_f32_16x16x32_bf16(a_h[i], b_l[j], acc[i][j], 0, 0, 0);
            }
    };

#define WAITV do { if (NT == 3) asm volatile("s_waitcnt vmcnt(16)" ::: "memory"); \
                   else         asm volatile("s_waitcnt vmcnt(12)" ::: "memory"); } while (0)
#define WAIT0 asm volatile("s_waitcnt vmcnt(0)" ::: "memory")
#define SCHED0 __builtin_amdgcn_sched_barrier(0)
#define RBAR  __builtin_amdgcn_s_barrier()

    const int nt = K >> 5;
    stage(0, 0);
    stage(1, 32);
    for (int t = 0; t + 2 < nt; ++t) {
        WAITV;                 // own stage(t) loads landed (stage(t+1) stays in flight)
        RBAR; SCHED0;          // all waves' stage(t) landed
        compute(t & 1);
        SCHED0; RBAR; SCHED0;  // all waves done reading buf[t&1]
        stage(t & 1, (t + 2) << 5);
    }
    WAITV;  RBAR; SCHED0; compute(nt & 1);        // t = nt-2  ((nt-2)&1 == nt&1)
    WAIT0;  RBAR; SCHED0; compute((nt - 1) & 1);  // t = nt-1

#undef WAITV
#undef WAIT0
#undef SCHED0
#undef RBAR

    float mult = 1.f;
    if (MODE == 1) mult = fmaxf(scal[4] / 127.f, 1e-8f);
    float amax = 0.f;
#pragma unroll
    for (int i = 0; i < 8; i++)
#pragma unroll
        for (int j = 0; j < 4; j++)
#pragma unroll
            for (int r = 0; r < 4; r++) {
                float v = acc[i][j][r] * mult;
                amax = fmaxf(amax, fabsf(v));
                size_t row = (size_t)(bm + i * 16 + quad * 4 + r);
                size_t col = (size_t)(bn + wave * 64 + j * 16 + lm);
                C[row * (size_t)N + col] = v;
            }
#pragma unroll
    for (int off = 32; off > 0; off >>= 1) amax = fmaxf(amax, __shfl_down(amax, off));
    if (lane == 0) wred[wave] = amax;
    __syncthreads();
    if (tid == 0) {
        float m = fmaxf(wred[0], wred[1]);
        int slot = (MODE == 0) ? ((bn < 4096) ? 0 : ((bn < 5120) ? 1 : 2)) : 5;
        atomicMax((unsigned int*)(scal + slot), __float_as_uint(m));
    }
}

// ---------------- quantize q/k/v + RoPE on q/k ----------------
// q/k: roped f32 -> bf16 hi + bf16 lo (per-head [b,h,s,d] layout)
// v:   integer codes (-127..127), exact in bf16, [b,hk,s,d] layout
__global__ void quant_rope_hilo_kernel(const float* __restrict__ qkv,
                                       unsigned short* __restrict__ Qh,
                                       unsigned short* __restrict__ Ql,
                                       unsigned short* __restrict__ Kh,
                                       unsigned short* __restrict__ Kl,
                                       unsigned short* __restrict__ Vc,
                                       const float* __restrict__ scal)
{
    int t = blockIdx.x * 256 + threadIdx.x;
    int f = t * 8;
    int r = f / DD;
    int c = f - r * DD;
    int b = r >> 10, sp = r & 1023;
    const float* src = qkv + (size_t)r * DD + c;
    float x[8] __attribute__((aligned(16)));
    *(float4*)(x)     = *(const float4*)(src);
    *(float4*)(x + 4) = *(const float4*)(src + 4);

    if (c < 5120) {  // q or k: quantize then rope, split hi/lo
        float s; int d; unsigned short *dh, *dl;
        if (c < 4096) {
            s = fmaxf(scal[0] / 127.f, 1e-8f);
            int head = c >> 7; d = c & 127;
            size_t off = (((size_t)(b * NH + head) * SS + sp) << 7) + d;
            dh = Qh + off; dl = Ql + off;
        } else {
            int cc = c - 4096;
            s = fmaxf(scal[1] / 127.f, 1e-8f);
            int head = cc >> 7; d = cc & 127;
            size_t off = (((size_t)(b * NKV + head) * SS + sp) << 7) + d;
            dh = Kh + off; dl = Kl + off;
        }
        int cp = (d < 64) ? (c + 64) : (c - 64);
        float sgn = (d < 64) ? -1.f : 1.f;
        const float* psrc = qkv + (size_t)r * DD + cp;
        float p[8] __attribute__((aligned(16)));
        *(float4*)(p)     = *(const float4*)(psrc);
        *(float4*)(p + 4) = *(const float4*)(psrc + 4);
        unsigned short h8[8] __attribute__((aligned(16)));
        unsigned short l8[8] __attribute__((aligned(16)));
#pragma unroll
        for (int i = 0; i < 8; i++) {
            float xq = fqs(x[i], s);
            float pq = fqs(p[i], s);
            int fi = (d + i) & 63;
            float inv = expf((float)fi * -0.14391156831212787f);  // 10000^(-fi/64)
            float ang = (float)sp * inv;
            float sn, cs;
            sincosf(ang, &sn, &cs);
            float o = xq * cs + sgn * pq * sn;
            unsigned short hb = f2b(o);
            h8[i] = hb;
            l8[i] = f2b(o - b2f(hb));
        }
        *(uint4*)(dh) = *(uint4*)h8;
        *(uint4*)(dl) = *(uint4*)l8;
    } else {        // v: integer codes only (exact in bf16)
        int cc = c - 5120;
        float s = fmaxf(scal[2] / 127.f, 1e-8f);
        int head = cc >> 7, d = cc & 127;
        unsigned short* dst = Vc + (((size_t)(b * NKV + head) * SS + sp) << 7) + d;
        unsigned short o8[8] __attribute__((aligned(16)));
#pragma unroll
        for (int i = 0; i < 8; i++) {
            float code = fminf(fmaxf(rintf(x[i] / s), -127.f), 127.f);
            o8[i] = f2b(code);
        }
        *(uint4*)(dst) = *(uint4*)o8;
    }
}

// ---------------- transpose V codes: Vc[bh][key][d] -> Vt[bh][d][key] ----------------
__global__ void vtrans_kernel(const unsigned short* __restrict__ Vc,
                              unsigned short* __restrict__ Vt)
{
    __shared__ __attribute__((aligned(16))) unsigned short L[64][72];
    const int dtile = blockIdx.x;   // 0..1
    const int ktile = blockIdx.y;   // 0..15
    const int bh    = blockIdx.z;   // 0..15
    const int tid = threadIdx.x;
#pragma unroll
    for (int it = 0; it < 2; it++) {
        int lin = it * 256 + tid;
        int row = lin >> 3, c8 = (lin & 7) * 8;
        *(uint4*)&L[row][c8] =
            *(const uint4*)(Vc + ((size_t)bh * SS + ktile * 64 + row) * HD + dtile * 64 + c8);
    }
    __syncthreads();
#pragma unroll
    for (int it = 0; it < 2; it++) {
        int lin = it * 256 + tid;
        int dr = lin >> 3, k8 = (lin & 7) * 8;
        unsigned short o8[8] __attribute__((aligned(16)));
#pragma unroll
        for (int i = 0; i < 8; i++) o8[i] = L[k8 + i][dr];
        *(uint4*)(Vt + ((size_t)bh * HD + dtile * 64 + dr) * SS + ktile * 64 + k8) = *(uint4*)o8;
    }
}

// ---------------- MFMA attention (hi/lo bf16 scores, integer-code PV) ----------------
// PASS 0: global max of clipped attn -> scal[3]   (QK^T only)
// PASS 1: quantized attn codes, PV on codes, O f32 out, |O| max -> scal[4]
template<int PASS>
__global__ __launch_bounds__(256, 2)
void attn_mfma_kernel(const unsigned short* __restrict__ Qh,
                      const unsigned short* __restrict__ Ql,
                      const unsigned short* __restrict__ Kh,
                      const unsigned short* __restrict__ Kl,
                      const unsigned short* __restrict__ Vt,
                      float* __restrict__ O,
                      float* __restrict__ scal)
{
    __shared__ __attribute__((aligned(16))) unsigned short Ps[PASS ? 4 : 1][16][72];
    __shared__ float wred[4];
    const int x = blockIdx.x;
    const int qc = x & 15, h = (x >> 4) & 31, b = x >> 9;
    const int hk = h >> 2;
    const int tid = threadIdx.x;
    const int wave = tid >> 6, lane = tid & 63;
    const int lm = lane & 15, quad = lane >> 4;
    const float coef = scal[7] * SCALE;
    float s_a = 1.f, s_av = 1.f;
    if (PASS) {
        s_a = fmaxf(scal[3] / 255.f, 1e-8f);
        float s_v = fmaxf(scal[2] / 127.f, 1e-8f);
        s_av = s_a * s_v;
    }

    const size_t qbase = ((size_t)((b * NH + h) * SS) + qc * 64 + wave * 16 + lm) * HD + quad * 8;
    short8 qh[4], ql[4];
#pragma unroll
    for (int kk = 0; kk < 4; kk++) {
        qh[kk] = *(const short8*)(Qh + qbase + kk * 32);
        ql[kk] = *(const short8*)(Ql + qbase + kk * 32);
    }
    const size_t kbase = (size_t)((b * NKV + hk) * SS) * HD + quad * 8;
    const size_t vbase = (size_t)((b * NKV + hk) * HD) * SS + quad * 8;

    const f4 z = {0.f, 0.f, 0.f, 0.f};
    f4 oacc[8];
    if (PASS) {
#pragma unroll
        for (int j2 = 0; j2 < 8; j2++) oacc[j2] = z;
    }
    float amax = 0.f;
    const int qg = qc * 64 + wave * 16 + quad * 4;

    for (int kt = 0; kt <= qc; kt++) {
        f4 acc[4];
#pragma unroll
        for (int j = 0; j < 4; j++) acc[j] = z;
        __builtin_amdgcn_s_setprio(1);
#pragma unroll
        for (int j = 0; j < 4; j++) {
            const size_t kb = kbase + (size_t)(kt * 64 + j * 16 + lm) * HD;
#pragma unroll
            for (int kk = 0; kk < 4; kk++) {
                short8 kh8 = *(const short8*)(Kh + kb + kk * 32);
                short8 kl8 = *(const short8*)(Kl + kb + kk * 32);
                acc[j] = __builtin_amdgcn_mfma_f32_16x16x32_bf16(qh[kk], kh8, acc[j], 0, 0, 0);
                acc[j] = __builtin_amdgcn_mfma_f32_16x16x32_bf16(ql[kk], kh8, acc[j], 0, 0, 0);
                acc[j] = __builtin_amdgcn_mfma_f32_16x16x32_bf16(qh[kk], kl8, acc[j], 0, 0, 0);
            }
        }
        __builtin_amdgcn_s_setprio(0);
        const bool diag = (kt == qc);
#pragma unroll
        for (int j = 0; j < 4; j++) {
            int kg = kt * 64 + j * 16 + lm;
#pragma unroll
            for (int r = 0; r < 4; r++) {
                bool ok = (!diag) || (kg <= qg + r);
                float a = 0.5f + coef * acc[j][r];
                a = fminf(fmaxf(a, 0.f), 1.f);
                if (PASS == 0) {
                    if (ok) amax = fmaxf(amax, a);
                } else {
                    float cd = ok ? fminf(rintf(a / s_a), 255.f) : 0.f;
                    Ps[wave][quad * 4 + r][j * 16 + lm] = f2b(cd);
                }
            }
        }
        if (PASS) {
            short8 pa0 = *(const short8*)&Ps[wave][lm][quad * 8];
            short8 pa1 = *(const short8*)&Ps[wave][lm][32 + quad * 8];
            __builtin_amdgcn_s_setprio(1);
#pragma unroll
            for (int j2 = 0; j2 < 8; j2++) {
                const unsigned short* vp = Vt + vbase + (size_t)(j2 * 16 + lm) * SS + kt * 64;
                short8 v0 = *(const short8*)(vp);
                short8 v1 = *(const short8*)(vp + 32);
                oacc[j2] = __builtin_amdgcn_mfma_f32_16x16x32_bf16(pa0, v0, oacc[j2], 0, 0, 0);
                oacc[j2] = __builtin_amdgcn_mfma_f32_16x16x32_bf16(pa1, v1, oacc[j2], 0, 0, 0);
            }
            __builtin_amdgcn_s_setprio(0);
        }
    }

    if (PASS == 0) {
#pragma unroll
        for (int off = 32; off > 0; off >>= 1) amax = fmaxf(amax, __shfl_down(amax, off));
        if (lane == 0) wred[wave] = amax;
        __syncthreads();
        if (tid == 0) {
            float m = fmaxf(fmaxf(wred[0], wred[1]), fmaxf(wred[2], wred[3]));
            atomicMax((unsigned int*)(scal + 3), __float_as_uint(m));
        }
    } else {
        float am = 0.f;
        const size_t orow = (size_t)(b * SS + qc * 64 + wave * 16 + quad * 4);
#pragma unroll
        for (int j2 = 0; j2 < 8; j2++)
#pragma unroll
            for (int r = 0; r < 4; r++) {
                float v = oacc[j2][r] * s_av;
                am = fmaxf(am, fabsf(v));
                O[(orow + r) * DQ + h * HD + j2 * 16 + lm] = v;
            }
#pragma unroll
        for (int off = 32; off > 0; off >>= 1) am = fmaxf(am, __shfl_down(am, off));
        if (lane == 0) wred[wave] = am;
        __syncthreads();
        if (tid == 0) {
            float m = fmaxf(fmaxf(wred[0], wred[1]), fmaxf(wred[2], wred[3]));
            atomicMax((unsigned int*)(scal + 4), __float_as_uint(m));
        }
    }
}

// ---------------- quantize O -> integer codes (bf16-exact) for GEMM2 ----------------
__global__ void quant_o_codes_kernel(const float* __restrict__ O,
                                     const float* __restrict__ scal,
                                     unsigned short* __restrict__ Oq)
{
    size_t t = (size_t)blockIdx.x * 256 + threadIdx.x;
    float s = fmaxf(scal[4] / 127.f, 1e-8f);
    float4 v = *(const float4*)(O + t * 4);
    unsigned short o[4] __attribute__((aligned(8)));
    o[0] = f2b(fminf(fmaxf(rintf(v.x / s), -127.f), 127.f));
    o[1] = f2b(fminf(fmaxf(rintf(v.y / s), -127.f), 127.f));
    o[2] = f2b(fminf(fmaxf(rintf(v.z / s), -127.f), 127.f));
    o[3] = f2b(fminf(fmaxf(rintf(v.w / s), -127.f), 127.f));
    *(uint2*)(Oq + t * 4) = *(uint2*)o;
}

// ---------------- final quantize -> f32 output ----------------
__global__ void final_q_kernel(const float* __restrict__ X,
                               const float* __restrict__ scal,
                               float* __restrict__ out)
{
    size_t t = (size_t)blockIdx.x * 256 + threadIdx.x;
    float s = fmaxf(scal[5] / 127.f, 1e-8f);
    float4 v = *(const float4*)(X + t * 4);
    float4 o;
    o.x = fqs(v.x, s);
    o.y = fqs(v.y, s);
    o.z = fqs(v.z, s);
    o.w = fqs(v.w, s);
    *(float4*)(out + t * 4) = o;
}

// ---------------- launch ----------------
extern "C" void kernel_launch(void* const* d_in, const int* in_sizes, int n_in,
                              void* d_out, int out_size, void* d_ws, size_t ws_size,
                              hipStream_t stream)
{
    const unsigned short* x      = (const unsigned short*)d_in[0];
    const unsigned short* w_qkv  = (const unsigned short*)d_in[1];
    const unsigned short* w_o    = (const unsigned short*)d_in[2];
    const unsigned short* slope  = (const unsigned short*)d_in[3];
    (void)in_sizes; (void)n_in; (void)out_size; (void)ws_size;

    char* ws = (char*)d_ws;
    float* scal          = (float*)ws;                         // slots 0..7 (256 B reserved)
    unsigned short* xh   = (unsigned short*)(ws + 256);        // 12.58M bf16
    unsigned short* xl   = (unsigned short*)(ws + 25166080);
    unsigned short* wqh  = (unsigned short*)(ws + 50331904);   // 37.75M bf16
    unsigned short* wql  = (unsigned short*)(ws + 125829376);
    float* qkv           = (float*)(ws + 201326848);           // 2048*6144 f32 (dead after rope)
    // attention buffers (inside the old Qf/Kf/Vf f32 footprint, ends 301990144):
    unsigned short* Qh   = (unsigned short*)(ws + 251658496);  // 16.78MB
    unsigned short* Ql   = (unsigned short*)(ws + 268435712);  // 16.78MB
    unsigned short* Kh   = (unsigned short*)(ws + 285212928);  // 4.19MB
    unsigned short* Kl   = (unsigned short*)(ws + 289407232);  // 4.19MB
    unsigned short* Vt   = (unsigned short*)(ws + 293601536);  // 4.19MB [bh][d][key]
    unsigned short* Vc   = (unsigned short*)(ws + 297795840);  // 4.19MB [bh][key][d] (ends 301990144)
    // regions dead after GEMM1 (xh/xl/wqh/wql) and after rope (qkv) are reused:
    unsigned short* woh  = (unsigned short*)(ws + 256);        // 16.78M bf16 (in xh/xl)
    unsigned short* wol  = (unsigned short*)(ws + 33554688);   // (xl tail + wqh head)
    float* O             = (float*)(ws + 67109376);            // 2048*4096 f32 (in wqh)
    unsigned short* Oqc  = (unsigned short*)(ws + 100663808);  // codes bf16 [ends 134218240]
    float* out2          = (float*)(ws + 201326848);           // 2048*4096 f32 (in dead qkv; NO alias w/ Oqc)
    float* outp          = (float*)d_out;                      // OUTPUT IS FLOAT32

    hipMemsetAsync(scal, 0, 256, stream);
    detect_kernel<<<1, 256, 0, stream>>>(x, scal);
    slope_kernel<<<1, 64, 0, stream>>>(slope, scal);
    convert_split_kernel<<<6144, 256, 0, stream>>>(x, xh, xl, scal);
    convert_split_kernel<<<18432, 256, 0, stream>>>(w_qkv, wqh, wql, scal);
    gemm_hilo_kernel<3, 0><<<768, 128, 0, stream>>>(xh, xl, wqh, wql, qkv,
                                                    MM, DD, DD, scal);
    quant_rope_hilo_kernel<<<6144, 256, 0, stream>>>(qkv, Qh, Ql, Kh, Kl, Vc, scal);
    vtrans_kernel<<<dim3(2, 16, 16), 256, 0, stream>>>(Vc, Vt);
    convert_split_kernel<<<8192, 256, 0, stream>>>(w_o, woh, wol, scal);  // after GEMM1 (aliased)
    attn_mfma_kernel<0><<<1024, 256, 0, stream>>>(Qh, Ql, Kh, Kl, Vt, O, scal);
    attn_mfma_kernel<1><<<1024, 256, 0, stream>>>(Qh, Ql, Kh, Kl, Vt, O, scal);
    quant_o_codes_kernel<<<8192, 256, 0, stream>>>(O, scal, Oqc);
    gemm_hilo_kernel<2, 1><<<512, 128, 0, stream>>>(Oqc, Oqc, woh, wol, out2,
                                                    MM, DQ, DQ, scal);
    final_q_kernel<<<8192, 256, 0, stream>>>(out2, scal, outp);
}

// Round 3
// 1591.188 us; speedup vs baseline: 1.1691x; 1.1691x over previous
//
#include <hip/hip_runtime.h>
#include <stdint.h>

// ---------------- problem constants ----------------
#define BB   2
#define SS   1024
#define NH   32
#define NKV  8
#define HD   128
#define DQ   4096      // NH*HD
#define DKV  1024      // NKV*HD
#define DD   6144      // DQ + 2*DKV
#define MM   2048      // B*S
#define SCALE 0.08838834764831845f   // 1/sqrt(128)

typedef __attribute__((ext_vector_type(8))) short short8;
typedef __attribute__((ext_vector_type(4))) float f4;

// ---------------- helpers ----------------
__device__ __forceinline__ float b2f(unsigned short b) {
    union { unsigned int u; float f; } v; v.u = ((unsigned int)b) << 16; return v.f;
}
__device__ __forceinline__ unsigned short f2b(float f) {
    union { float f; unsigned int u; } v; v.f = f;
    unsigned int u = v.u;
    unsigned int r = u + 0x7fffu + ((u >> 16) & 1u);
    return (unsigned short)(r >> 16);
}
__device__ __forceinline__ float fqs(float x, float s) {   // symmetric fake-quant, qp=127
    return fminf(fmaxf(rintf(x / s), -127.f), 127.f) * s;
}

typedef const unsigned int __attribute__((address_space(1)))* gas_ptr;
typedef unsigned int __attribute__((address_space(3)))* las_ptr;
__device__ __forceinline__ void gl_lds16(const void* g, void* l) {
    __builtin_amdgcn_global_load_lds((gas_ptr)(uintptr_t)g,
                                     (las_ptr)(unsigned int)(uintptr_t)l, 16, 0, 0);
}

// ---------------- dtype detector: scal[6] = 1.0 if inputs are f32 ----------------
__global__ void detect_kernel(const unsigned short* __restrict__ x, float* scal) {
    __shared__ float w[4];
    int tid = threadIdx.x;
    float m = 0.f;
    for (int i = tid; i < 65536; i += 256) m = fmaxf(m, fabsf(b2f(x[i])));
#pragma unroll
    for (int off = 32; off > 0; off >>= 1) m = fmaxf(m, __shfl_down(m, off));
    if ((tid & 63) == 0) w[tid >> 6] = m;
    __syncthreads();
    if (tid == 0) {
        float mm = fmaxf(fmaxf(w[0], w[1]), fmaxf(w[2], w[3]));
        scal[6] = (mm > 1e4f) ? 1.0f : 0.0f;
    }
}

__global__ void slope_kernel(const unsigned short* __restrict__ sp, float* scal) {
    if (threadIdx.x == 0)
        scal[7] = (scal[6] > 0.5f) ? ((const float*)sp)[0] : b2f(sp[0]);
}

// ---------------- split input (f32 or bf16) -> bf16 hi + bf16 lo ----------------
__global__ void convert_split_kernel(const unsigned short* __restrict__ src,
                                     unsigned short* __restrict__ hi,
                                     unsigned short* __restrict__ lo,
                                     const float* __restrict__ scal) {
    size_t t = (size_t)blockIdx.x * 256 + threadIdx.x;
    float v[8] __attribute__((aligned(16)));
    if (scal[6] > 0.5f) {
        const float* s = (const float*)src + t * 8;
        *(float4*)(v)     = *(const float4*)(s);
        *(float4*)(v + 4) = *(const float4*)(s + 4);
    } else {
        unsigned short u[8] __attribute__((aligned(16)));
        *(uint4*)u = *(const uint4*)(src + t * 8);
#pragma unroll
        for (int i = 0; i < 8; i++) v[i] = b2f(u[i]);
    }
    unsigned short h8[8] __attribute__((aligned(16)));
    unsigned short l8[8] __attribute__((aligned(16)));
#pragma unroll
    for (int i = 0; i < 8; i++) {
        unsigned short h = f2b(v[i]);
        h8[i] = h;
        l8[i] = f2b(v[i] - b2f(h));
    }
    *(uint4*)(hi + t * 8) = *(uint4*)h8;
    *(uint4*)(lo + t * 8) = *(uint4*)l8;
}

// ---------------- hi/lo GEMM  C[M,N] = A[M,K] * B[N,K]^T  (f32-accurate) ----------------
// NT=3: C = Ah Bh + Al Bh + Ah Bl   (MODE 0: qkv -> amax slots 0..2)
// NT=2: C = (Ah Bh + Ah Bl) * s_O   (MODE 1: out -> amax slot 5)
// Round-1 geometry (256 thr, 4 waves, 64x64 wave tiles, 128x128 block tile, BK=32)
// + chunk-XOR LDS swizzle (both-sides: pre-swizzled global src + swizzled ds_read)
// + double-buffered counted-vmcnt pipeline (stage t+2 in flight across raw barriers).
template<int NT, int MODE>
__global__ __launch_bounds__(256, 2)
void gemm_hilo_kernel(const unsigned short* __restrict__ Ah,
                      const unsigned short* __restrict__ Al,
                      const unsigned short* __restrict__ Bh,
                      const unsigned short* __restrict__ Bl,
                      float* __restrict__ C,
                      int M, int N, int K,
                      float* __restrict__ scal)
{
    constexpr int PA    = 128 * 32;                  // shorts per panel
    constexpr int OAL   = PA;                        // Al (NT3 only)
    constexpr int OBH   = (NT == 3) ? 2 * PA : PA;
    constexpr int OBL   = OBH + PA;
    constexpr int BUFSH = OBL + PA;                  // shorts per buffer
    __shared__ unsigned short lds[2 * BUFSH];
    __shared__ float wred[4];

    const int tid = threadIdx.x;
    const int bn = blockIdx.x << 7;
    const int bm = blockIdx.y << 7;
    const int wave = tid >> 6, lane = tid & 63;
    const int wm = (wave >> 1) << 6, wn = (wave & 1) << 6;
    const int lm = lane & 15, quad = lane >> 4;
    const int qx = quad ^ ((lm >> 1) & 3);           // read-side swizzle

    const f4 z = {0.f, 0.f, 0.f, 0.f};
    f4 acc[4][4];
#pragma unroll
    for (int i = 0; i < 4; i++)
#pragma unroll
        for (int j = 0; j < 4; j++) acc[i][j] = z;

    // staging: thread i stages row i>>2 (and +64), swizzled col chunk.
    // note ((r+64)>>1)&3 == (r>>1)&3, so one swizzled column serves both rows.
    const int r0 = tid >> 2;
    const int cs = ((tid & 3) ^ ((r0 >> 1) & 3)) * 8;
    const size_t ra0 = (size_t)(bm + r0) * K + cs;
    const size_t ra1 = (size_t)(bm + r0 + 64) * K + cs;
    const size_t rb0 = (size_t)(bn + r0) * K + cs;
    const size_t rb1 = (size_t)(bn + r0 + 64) * K + cs;
    const int l0 = tid * 8, l1 = (tid + 256) * 8;

    auto stage = [&](int bsel, int k0) {
        unsigned short* L = lds + bsel * BUFSH;
        gl_lds16(Ah + ra0 + k0, L + l0);
        gl_lds16(Ah + ra1 + k0, L + l1);
        if (NT == 3) {
            gl_lds16(Al + ra0 + k0, L + OAL + l0);
            gl_lds16(Al + ra1 + k0, L + OAL + l1);
        }
        gl_lds16(Bh + rb0 + k0, L + OBH + l0);
        gl_lds16(Bh + rb1 + k0, L + OBH + l1);
        gl_lds16(Bl + rb0 + k0, L + OBL + l0);
        gl_lds16(Bl + rb1 + k0, L + OBL + l1);
    };

    auto compute = [&](int bsel) {
        const unsigned short* L = lds + bsel * BUFSH;
        short8 a_h[4], b_h[4], b_l[4];
        short8 a_l[(NT == 3) ? 4 : 1];
#pragma unroll
        for (int t = 0; t < 4; t++) {
            int ro = (wm + t * 16 + lm) * 32 + qx * 8;
            a_h[t] = *(const short8*)(L + ro);
            if (NT == 3) a_l[t] = *(const short8*)(L + OAL + ro);
        }
#pragma unroll
        for (int t = 0; t < 4; t++) {
            int ro = (wn + t * 16 + lm) * 32 + qx * 8;
            b_h[t] = *(const short8*)(L + OBH + ro);
            b_l[t] = *(const short8*)(L + OBL + ro);
        }
#pragma unroll
        for (int i = 0; i < 4; i++)
#pragma unroll
            for (int j = 0; j < 4; j++) {
                acc[i][j] = __builtin_amdgcn_mfma_f32_16x16x32_bf16(a_h[i], b_h[j], acc[i][j], 0, 0, 0);
                if (NT == 3)
                    acc[i][j] = __builtin_amdgcn_mfma_f32_16x16x32_bf16(a_l[i], b_h[j], acc[i][j], 0, 0, 0);
                acc[i][j] = __builtin_amdgcn_mfma_f32_16x16x32_bf16(a_h[i], b_l[j], acc[i][j], 0, 0, 0);
            }
    };

#define WAITV do { if (NT == 3) asm volatile("s_waitcnt vmcnt(8)" ::: "memory"); \
                   else         asm volatile("s_waitcnt vmcnt(6)" ::: "memory"); } while (0)
#define WAIT0 asm volatile("s_waitcnt vmcnt(0)" ::: "memory")
#define SCHED0 __builtin_amdgcn_sched_barrier(0)
#define RBAR  __builtin_amdgcn_s_barrier()

    const int nt = K >> 5;
    stage(0, 0);
    stage(1, 32);
    for (int t = 0; t + 2 < nt; ++t) {
        WAITV;                 // own stage(t) loads landed (stage(t+1) stays in flight)
        RBAR; SCHED0;          // all waves' stage(t) landed
        compute(t & 1);
        SCHED0; RBAR; SCHED0;  // all waves done reading buf[t&1]
        stage(t & 1, (t + 2) << 5);
    }
    WAITV;  RBAR; SCHED0; compute(nt & 1);        // t = nt-2  ((nt-2)&1 == nt&1)
    WAIT0;  RBAR; SCHED0; compute((nt - 1) & 1);  // t = nt-1

#undef WAITV
#undef WAIT0
#undef SCHED0
#undef RBAR

    float mult = 1.f;
    if (MODE == 1) mult = fmaxf(scal[4] / 127.f, 1e-8f);
    float amax = 0.f;
#pragma unroll
    for (int i = 0; i < 4; i++)
#pragma unroll
        for (int j = 0; j < 4; j++)
#pragma unroll
            for (int r = 0; r < 4; r++) {
                float v = acc[i][j][r] * mult;
                amax = fmaxf(amax, fabsf(v));
                size_t row = (size_t)(bm + wm + i * 16 + quad * 4 + r);
                size_t col = (size_t)(bn + wn + j * 16 + lm);
                C[row * (size_t)N + col] = v;
            }
#pragma unroll
    for (int off = 32; off > 0; off >>= 1) amax = fmaxf(amax, __shfl_down(amax, off));
    if (lane == 0) wred[wave] = amax;
    __syncthreads();
    if (tid == 0) {
        float m = fmaxf(fmaxf(wred[0], wred[1]), fmaxf(wred[2], wred[3]));
        int slot = (MODE == 0) ? ((bn < 4096) ? 0 : ((bn < 5120) ? 1 : 2)) : 5;
        atomicMax((unsigned int*)(scal + slot), __float_as_uint(m));
    }
}

// ---------------- quantize q/k/v + RoPE on q/k ----------------
// q/k: roped f32 -> bf16 hi + bf16 lo (per-head [b,h,s,d] layout)
// v:   integer codes (-127..127), exact in bf16, [b,hk,s,d] layout
__global__ void quant_rope_hilo_kernel(const float* __restrict__ qkv,
                                       unsigned short* __restrict__ Qh,
                                       unsigned short* __restrict__ Ql,
                                       unsigned short* __restrict__ Kh,
                                       unsigned short* __restrict__ Kl,
                                       unsigned short* __restrict__ Vc,
                                       const float* __restrict__ scal)
{
    int t = blockIdx.x * 256 + threadIdx.x;
    int f = t * 8;
    int r = f / DD;
    int c = f - r * DD;
    int b = r >> 10, sp = r & 1023;
    const float* src = qkv + (size_t)r * DD + c;
    float x[8] __attribute__((aligned(16)));
    *(float4*)(x)     = *(const float4*)(src);
    *(float4*)(x + 4) = *(const float4*)(src + 4);

    if (c < 5120) {  // q or k: quantize then rope, split hi/lo
        float s; int d; unsigned short *dh, *dl;
        if (c < 4096) {
            s = fmaxf(scal[0] / 127.f, 1e-8f);
            int head = c >> 7; d = c & 127;
            size_t off = (((size_t)(b * NH + head) * SS + sp) << 7) + d;
            dh = Qh + off; dl = Ql + off;
        } else {
            int cc = c - 4096;
            s = fmaxf(scal[1] / 127.f, 1e-8f);
            int head = cc >> 7; d = cc & 127;
            size_t off = (((size_t)(b * NKV + head) * SS + sp) << 7) + d;
            dh = Kh + off; dl = Kl + off;
        }
        int cp = (d < 64) ? (c + 64) : (c - 64);
        float sgn = (d < 64) ? -1.f : 1.f;
        const float* psrc = qkv + (size_t)r * DD + cp;
        float p[8] __attribute__((aligned(16)));
        *(float4*)(p)     = *(const float4*)(psrc);
        *(float4*)(p + 4) = *(const float4*)(psrc + 4);
        unsigned short h8[8] __attribute__((aligned(16)));
        unsigned short l8[8] __attribute__((aligned(16)));
#pragma unroll
        for (int i = 0; i < 8; i++) {
            float xq = fqs(x[i], s);
            float pq = fqs(p[i], s);
            int fi = (d + i) & 63;
            float inv = expf((float)fi * -0.14391156831212787f);  // 10000^(-fi/64)
            float ang = (float)sp * inv;
            float sn, cs;
            sincosf(ang, &sn, &cs);
            float o = xq * cs + sgn * pq * sn;
            unsigned short hb = f2b(o);
            h8[i] = hb;
            l8[i] = f2b(o - b2f(hb));
        }
        *(uint4*)(dh) = *(uint4*)h8;
        *(uint4*)(dl) = *(uint4*)l8;
    } else {        // v: integer codes only (exact in bf16)
        int cc = c - 5120;
        float s = fmaxf(scal[2] / 127.f, 1e-8f);
        int head = cc >> 7, d = cc & 127;
        unsigned short* dst = Vc + (((size_t)(b * NKV + head) * SS + sp) << 7) + d;
        unsigned short o8[8] __attribute__((aligned(16)));
#pragma unroll
        for (int i = 0; i < 8; i++) {
            float code = fminf(fmaxf(rintf(x[i] / s), -127.f), 127.f);
            o8[i] = f2b(code);
        }
        *(uint4*)(dst) = *(uint4*)o8;
    }
}

// ---------------- transpose V codes: Vc[bh][key][d] -> Vt[bh][d][key] ----------------
__global__ void vtrans_kernel(const unsigned short* __restrict__ Vc,
                              unsigned short* __restrict__ Vt)
{
    __shared__ __attribute__((aligned(16))) unsigned short L[64][72];
    const int dtile = blockIdx.x;   // 0..1
    const int ktile = blockIdx.y;   // 0..15
    const int bh    = blockIdx.z;   // 0..15
    const int tid = threadIdx.x;
#pragma unroll
    for (int it = 0; it < 2; it++) {
        int lin = it * 256 + tid;
        int row = lin >> 3, c8 = (lin & 7) * 8;
        *(uint4*)&L[row][c8] =
            *(const uint4*)(Vc + ((size_t)bh * SS + ktile * 64 + row) * HD + dtile * 64 + c8);
    }
    __syncthreads();
#pragma unroll
    for (int it = 0; it < 2; it++) {
        int lin = it * 256 + tid;
        int dr = lin >> 3, k8 = (lin & 7) * 8;
        unsigned short o8[8] __attribute__((aligned(16)));
#pragma unroll
        for (int i = 0; i < 8; i++) o8[i] = L[k8 + i][dr];
        *(uint4*)(Vt + ((size_t)bh * HD + dtile * 64 + dr) * SS + ktile * 64 + k8) = *(uint4*)o8;
    }
}

// ---------------- MFMA attention (hi/lo bf16 scores, integer-code PV) ----------------
// PASS 0: global max of clipped attn -> scal[3]   (QK^T only)
// PASS 1: quantized attn codes, PV on codes, O f32 out, |O| max -> scal[4]
template<int PASS>
__global__ __launch_bounds__(256, 2)
void attn_mfma_kernel(const unsigned short* __restrict__ Qh,
                      const unsigned short* __restrict__ Ql,
                      const unsigned short* __restrict__ Kh,
                      const unsigned short* __restrict__ Kl,
                      const unsigned short* __restrict__ Vt,
                      float* __restrict__ O,
                      float* __restrict__ scal)
{
    __shared__ __attribute__((aligned(16))) unsigned short Ps[PASS ? 4 : 1][16][72];
    __shared__ float wred[4];
    const int x = blockIdx.x;
    const int qc = x & 15, h = (x >> 4) & 31, b = x >> 9;
    const int hk = h >> 2;
    const int tid = threadIdx.x;
    const int wave = tid >> 6, lane = tid & 63;
    const int lm = lane & 15, quad = lane >> 4;
    const float coef = scal[7] * SCALE;
    float s_a = 1.f, s_av = 1.f;
    if (PASS) {
        s_a = fmaxf(scal[3] / 255.f, 1e-8f);
        float s_v = fmaxf(scal[2] / 127.f, 1e-8f);
        s_av = s_a * s_v;
    }

    const size_t qbase = ((size_t)((b * NH + h) * SS) + qc * 64 + wave * 16 + lm) * HD + quad * 8;
    short8 qh[4], ql[4];
#pragma unroll
    for (int kk = 0; kk < 4; kk++) {
        qh[kk] = *(const short8*)(Qh + qbase + kk * 32);
        ql[kk] = *(const short8*)(Ql + qbase + kk * 32);
    }
    const size_t kbase = (size_t)((b * NKV + hk) * SS) * HD + quad * 8;
    const size_t vbase = (size_t)((b * NKV + hk) * HD) * SS + quad * 8;

    const f4 z = {0.f, 0.f, 0.f, 0.f};
    f4 oacc[8];
    if (PASS) {
#pragma unroll
        for (int j2 = 0; j2 < 8; j2++) oacc[j2] = z;
    }
    float amax = 0.f;
    const int qg = qc * 64 + wave * 16 + quad * 4;

    for (int kt = 0; kt <= qc; kt++) {
        f4 acc[4];
#pragma unroll
        for (int j = 0; j < 4; j++) acc[j] = z;
        __builtin_amdgcn_s_setprio(1);
#pragma unroll
        for (int j = 0; j < 4; j++) {
            const size_t kb = kbase + (size_t)(kt * 64 + j * 16 + lm) * HD;
#pragma unroll
            for (int kk = 0; kk < 4; kk++) {
                short8 kh8 = *(const short8*)(Kh + kb + kk * 32);
                short8 kl8 = *(const short8*)(Kl + kb + kk * 32);
                acc[j] = __builtin_amdgcn_mfma_f32_16x16x32_bf16(qh[kk], kh8, acc[j], 0, 0, 0);
                acc[j] = __builtin_amdgcn_mfma_f32_16x16x32_bf16(ql[kk], kh8, acc[j], 0, 0, 0);
                acc[j] = __builtin_amdgcn_mfma_f32_16x16x32_bf16(qh[kk], kl8, acc[j], 0, 0, 0);
            }
        }
        __builtin_amdgcn_s_setprio(0);
        const bool diag = (kt == qc);
#pragma unroll
        for (int j = 0; j < 4; j++) {
            int kg = kt * 64 + j * 16 + lm;
#pragma unroll
            for (int r = 0; r < 4; r++) {
                bool ok = (!diag) || (kg <= qg + r);
                float a = 0.5f + coef * acc[j][r];
                a = fminf(fmaxf(a, 0.f), 1.f);
                if (PASS == 0) {
                    if (ok) amax = fmaxf(amax, a);
                } else {
                    float cd = ok ? fminf(rintf(a / s_a), 255.f) : 0.f;
                    Ps[wave][quad * 4 + r][j * 16 + lm] = f2b(cd);
                }
            }
        }
        if (PASS) {
            short8 pa0 = *(const short8*)&Ps[wave][lm][quad * 8];
            short8 pa1 = *(const short8*)&Ps[wave][lm][32 + quad * 8];
            __builtin_amdgcn_s_setprio(1);
#pragma unroll
            for (int j2 = 0; j2 < 8; j2++) {
                const unsigned short* vp = Vt + vbase + (size_t)(j2 * 16 + lm) * SS + kt * 64;
                short8 v0 = *(const short8*)(vp);
                short8 v1 = *(const short8*)(vp + 32);
                oacc[j2] = __builtin_amdgcn_mfma_f32_16x16x32_bf16(pa0, v0, oacc[j2], 0, 0, 0);
                oacc[j2] = __builtin_amdgcn_mfma_f32_16x16x32_bf16(pa1, v1, oacc[j2], 0, 0, 0);
            }
            __builtin_amdgcn_s_setprio(0);
        }
    }

    if (PASS == 0) {
#pragma unroll
        for (int off = 32; off > 0; off >>= 1) amax = fmaxf(amax, __shfl_down(amax, off));
        if (lane == 0) wred[wave] = amax;
        __syncthreads();
        if (tid == 0) {
            float m = fmaxf(fmaxf(wred[0], wred[1]), fmaxf(wred[2], wred[3]));
            atomicMax((unsigned int*)(scal + 3), __float_as_uint(m));
        }
    } else {
        float am = 0.f;
        const size_t orow = (size_t)(b * SS + qc * 64 + wave * 16 + quad * 4);
#pragma unroll
        for (int j2 = 0; j2 < 8; j2++)
#pragma unroll
            for (int r = 0; r < 4; r++) {
                float v = oacc[j2][r] * s_av;
                am = fmaxf(am, fabsf(v));
                O[(orow + r) * DQ + h * HD + j2 * 16 + lm] = v;
            }
#pragma unroll
        for (int off = 32; off > 0; off >>= 1) am = fmaxf(am, __shfl_down(am, off));
        if (lane == 0) wred[wave] = am;
        __syncthreads();
        if (tid == 0) {
            float m = fmaxf(fmaxf(wred[0], wred[1]), fmaxf(wred[2], wred[3]));
            atomicMax((unsigned int*)(scal + 4), __float_as_uint(m));
        }
    }
}

// ---------------- quantize O -> integer codes (bf16-exact) for GEMM2 ----------------
__global__ void quant_o_codes_kernel(const float* __restrict__ O,
                                     const float* __restrict__ scal,
                                     unsigned short* __restrict__ Oq)
{
    size_t t = (size_t)blockIdx.x * 256 + threadIdx.x;
    float s = fmaxf(scal[4] / 127.f, 1e-8f);
    float4 v = *(const float4*)(O + t * 4);
    unsigned short o[4] __attribute__((aligned(8)));
    o[0] = f2b(fminf(fmaxf(rintf(v.x / s), -127.f), 127.f));
    o[1] = f2b(fminf(fmaxf(rintf(v.y / s), -127.f), 127.f));
    o[2] = f2b(fminf(fmaxf(rintf(v.z / s), -127.f), 127.f));
    o[3] = f2b(fminf(fmaxf(rintf(v.w / s), -127.f), 127.f));
    *(uint2*)(Oq + t * 4) = *(uint2*)o;
}

// ---------------- final quantize -> f32 output ----------------
__global__ void final_q_kernel(const float* __restrict__ X,
                               const float* __restrict__ scal,
                               float* __restrict__ out)
{
    size_t t = (size_t)blockIdx.x * 256 + threadIdx.x;
    float s = fmaxf(scal[5] / 127.f, 1e-8f);
    float4 v = *(const float4*)(X + t * 4);
    float4 o;
    o.x = fqs(v.x, s);
    o.y = fqs(v.y, s);
    o.z = fqs(v.z, s);
    o.w = fqs(v.w, s);
    *(float4*)(out + t * 4) = o;
}

// ---------------- launch ----------------
extern "C" void kernel_launch(void* const* d_in, const int* in_sizes, int n_in,
                              void* d_out, int out_size, void* d_ws, size_t ws_size,
                              hipStream_t stream)
{
    const unsigned short* x      = (const unsigned short*)d_in[0];
    const unsigned short* w_qkv  = (const unsigned short*)d_in[1];
    const unsigned short* w_o    = (const unsigned short*)d_in[2];
    const unsigned short* slope  = (const unsigned short*)d_in[3];
    (void)in_sizes; (void)n_in; (void)out_size; (void)ws_size;

    char* ws = (char*)d_ws;
    float* scal          = (float*)ws;                         // slots 0..7 (256 B reserved)
    unsigned short* xh   = (unsigned short*)(ws + 256);        // 12.58M bf16
    unsigned short* xl   = (unsigned short*)(ws + 25166080);
    unsigned short* wqh  = (unsigned short*)(ws + 50331904);   // 37.75M bf16
    unsigned short* wql  = (unsigned short*)(ws + 125829376);
    float* qkv           = (float*)(ws + 201326848);           // 2048*6144 f32 (dead after rope)
    // attention buffers (inside the old Qf/Kf/Vf f32 footprint, ends 301990144):
    unsigned short* Qh   = (unsigned short*)(ws + 251658496);  // 16.78MB
    unsigned short* Ql   = (unsigned short*)(ws + 268435712);  // 16.78MB
    unsigned short* Kh   = (unsigned short*)(ws + 285212928);  // 4.19MB
    unsigned short* Kl   = (unsigned short*)(ws + 289407232);  // 4.19MB
    unsigned short* Vt   = (unsigned short*)(ws + 293601536);  // 4.19MB [bh][d][key]
    unsigned short* Vc   = (unsigned short*)(ws + 297795840);  // 4.19MB [bh][key][d] (ends 301990144)
    // regions dead after GEMM1 (xh/xl/wqh/wql) and after rope (qkv) are reused:
    unsigned short* woh  = (unsigned short*)(ws + 256);        // 16.78M bf16 (in xh/xl)
    unsigned short* wol  = (unsigned short*)(ws + 33554688);   // (xl tail + wqh head)
    float* O             = (float*)(ws + 67109376);            // 2048*4096 f32 (in wqh)
    unsigned short* Oqc  = (unsigned short*)(ws + 100663808);  // codes bf16 [ends 134218240]
    float* out2          = (float*)(ws + 201326848);           // 2048*4096 f32 (in dead qkv; NO alias w/ Oqc)
    float* outp          = (float*)d_out;                      // OUTPUT IS FLOAT32

    hipMemsetAsync(scal, 0, 256, stream);
    detect_kernel<<<1, 256, 0, stream>>>(x, scal);
    slope_kernel<<<1, 64, 0, stream>>>(slope, scal);
    convert_split_kernel<<<6144, 256, 0, stream>>>(x, xh, xl, scal);
    convert_split_kernel<<<18432, 256, 0, stream>>>(w_qkv, wqh, wql, scal);
    gemm_hilo_kernel<3, 0><<<dim3(48, 16), 256, 0, stream>>>(xh, xl, wqh, wql, qkv,
                                                             MM, DD, DD, scal);
    quant_rope_hilo_kernel<<<6144, 256, 0, stream>>>(qkv, Qh, Ql, Kh, Kl, Vc, scal);
    vtrans_kernel<<<dim3(2, 16, 16), 256, 0, stream>>>(Vc, Vt);
    convert_split_kernel<<<8192, 256, 0, stream>>>(w_o, woh, wol, scal);  // after GEMM1 (aliased)
    attn_mfma_kernel<0><<<1024, 256, 0, stream>>>(Qh, Ql, Kh, Kl, Vt, O, scal);
    attn_mfma_kernel<1><<<1024, 256, 0, stream>>>(Qh, Ql, Kh, Kl, Vt, O, scal);
    quant_o_codes_kernel<<<8192, 256, 0, stream>>>(O, scal, Oqc);
    gemm_hilo_kernel<2, 1><<<dim3(32, 16), 256, 0, stream>>>(Oqc, Oqc, woh, wol, out2,
                                                             MM, DQ, DQ, scal);
    final_q_kernel<<<8192, 256, 0, stream>>>(out2, scal, outp);
}

// Round 4
// 1455.104 us; speedup vs baseline: 1.2785x; 1.0935x over previous
//
#include <hip/hip_runtime.h>
#include <stdint.h>

// ---------------- problem constants ----------------
#define BB   2
#define SS   1024
#define NH   32
#define NKV  8
#define HD   128
#define DQ   4096      // NH*HD
#define DKV  1024      // NKV*HD
#define DD   6144      // DQ + 2*DKV
#define MM   2048      // B*S
#define SCALE 0.08838834764831845f   // 1/sqrt(128)

typedef __attribute__((ext_vector_type(8))) short short8;
typedef __attribute__((ext_vector_type(4))) float f4;

// ---------------- helpers ----------------
__device__ __forceinline__ float b2f(unsigned short b) {
    union { unsigned int u; float f; } v; v.u = ((unsigned int)b) << 16; return v.f;
}
__device__ __forceinline__ unsigned short f2b(float f) {
    union { float f; unsigned int u; } v; v.f = f;
    unsigned int u = v.u;
    unsigned int r = u + 0x7fffu + ((u >> 16) & 1u);
    return (unsigned short)(r >> 16);
}
__device__ __forceinline__ float fqs(float x, float s) {   // symmetric fake-quant, qp=127
    return fminf(fmaxf(rintf(x / s), -127.f), 127.f) * s;
}

typedef const unsigned int __attribute__((address_space(1)))* gas_ptr;
typedef unsigned int __attribute__((address_space(3)))* las_ptr;
__device__ __forceinline__ void gl_lds16(const void* g, void* l) {
    __builtin_amdgcn_global_load_lds((gas_ptr)(uintptr_t)g,
                                     (las_ptr)(unsigned int)(uintptr_t)l, 16, 0, 0);
}

// ---------------- dtype detector: scal[6] = 1.0 if inputs are f32 ----------------
__global__ void detect_kernel(const unsigned short* __restrict__ x, float* scal) {
    __shared__ float w[4];
    int tid = threadIdx.x;
    float m = 0.f;
    for (int i = tid; i < 65536; i += 256) m = fmaxf(m, fabsf(b2f(x[i])));
#pragma unroll
    for (int off = 32; off > 0; off >>= 1) m = fmaxf(m, __shfl_down(m, off));
    if ((tid & 63) == 0) w[tid >> 6] = m;
    __syncthreads();
    if (tid == 0) {
        float mm = fmaxf(fmaxf(w[0], w[1]), fmaxf(w[2], w[3]));
        scal[6] = (mm > 1e4f) ? 1.0f : 0.0f;
    }
}

__global__ void slope_kernel(const unsigned short* __restrict__ sp, float* scal) {
    if (threadIdx.x == 0)
        scal[7] = (scal[6] > 0.5f) ? ((const float*)sp)[0] : b2f(sp[0]);
}

// ---------------- split input (f32 or bf16) -> bf16 hi + bf16 lo ----------------
__global__ void convert_split_kernel(const unsigned short* __restrict__ src,
                                     unsigned short* __restrict__ hi,
                                     unsigned short* __restrict__ lo,
                                     const float* __restrict__ scal) {
    size_t t = (size_t)blockIdx.x * 256 + threadIdx.x;
    float v[8] __attribute__((aligned(16)));
    if (scal[6] > 0.5f) {
        const float* s = (const float*)src + t * 8;
        *(float4*)(v)     = *(const float4*)(s);
        *(float4*)(v + 4) = *(const float4*)(s + 4);
    } else {
        unsigned short u[8] __attribute__((aligned(16)));
        *(uint4*)u = *(const uint4*)(src + t * 8);
#pragma unroll
        for (int i = 0; i < 8; i++) v[i] = b2f(u[i]);
    }
    unsigned short h8[8] __attribute__((aligned(16)));
    unsigned short l8[8] __attribute__((aligned(16)));
#pragma unroll
    for (int i = 0; i < 8; i++) {
        unsigned short h = f2b(v[i]);
        h8[i] = h;
        l8[i] = f2b(v[i] - b2f(h));
    }
    *(uint4*)(hi + t * 8) = *(uint4*)h8;
    *(uint4*)(lo + t * 8) = *(uint4*)l8;
}

// ---------------- hi/lo GEMM  C[M,N] = A[M,K] * B[N,K]^T  (f32-accurate) ----------------
// NT=3: C = Ah Bh + Al Bh + Ah Bl   (MODE 0: qkv -> amax slots 0..2)
// NT=2: C = (Ah Bh + Ah Bl) * s_O   (MODE 1: out -> amax slot 5)
// 256 thr, 4 waves, 64x64 wave tiles, 128x128 block tile, BK=32.
// Single-buffered LDS (32 KB NT3 / 24 KB NT2) -> 4+ blocks/CU for TLP,
// chunk-XOR swizzle (both-sides) -> zero bank conflicts.
template<int NT, int MODE>
__global__ __launch_bounds__(256, 4)
void gemm_hilo_kernel(const unsigned short* __restrict__ Ah,
                      const unsigned short* __restrict__ Al,
                      const unsigned short* __restrict__ Bh,
                      const unsigned short* __restrict__ Bl,
                      float* __restrict__ C,
                      int M, int N, int K,
                      float* __restrict__ scal)
{
    constexpr int PA    = 128 * 32;                  // shorts per panel
    constexpr int OAL   = PA;                        // Al (NT3 only)
    constexpr int OBH   = (NT == 3) ? 2 * PA : PA;
    constexpr int OBL   = OBH + PA;
    __shared__ unsigned short lds[OBL + PA];
    __shared__ float wred[4];

    const int tid = threadIdx.x;
    const int bn = blockIdx.x << 7;
    const int bm = blockIdx.y << 7;
    const int wave = tid >> 6, lane = tid & 63;
    const int wm = (wave >> 1) << 6, wn = (wave & 1) << 6;
    const int lm = lane & 15, quad = lane >> 4;
    const int qx = quad ^ ((lm >> 1) & 3);           // read-side swizzle

    const f4 z = {0.f, 0.f, 0.f, 0.f};
    f4 acc[4][4];
#pragma unroll
    for (int i = 0; i < 4; i++)
#pragma unroll
        for (int j = 0; j < 4; j++) acc[i][j] = z;

    // staging: thread i stages row i>>2 (and +64), swizzled col chunk.
    // ((r+64)>>1)&3 == (r>>1)&3, so one swizzled column serves both rows.
    const int r0 = tid >> 2;
    const int cs = ((tid & 3) ^ ((r0 >> 1) & 3)) * 8;
    const size_t ra0 = (size_t)(bm + r0) * K + cs;
    const size_t ra1 = (size_t)(bm + r0 + 64) * K + cs;
    const size_t rb0 = (size_t)(bn + r0) * K + cs;
    const size_t rb1 = (size_t)(bn + r0 + 64) * K + cs;
    const int l0 = tid * 8, l1 = (tid + 256) * 8;

    for (int k0 = 0; k0 < K; k0 += 32) {
        gl_lds16(Ah + ra0 + k0, lds + l0);
        gl_lds16(Ah + ra1 + k0, lds + l1);
        if (NT == 3) {
            gl_lds16(Al + ra0 + k0, lds + OAL + l0);
            gl_lds16(Al + ra1 + k0, lds + OAL + l1);
        }
        gl_lds16(Bh + rb0 + k0, lds + OBH + l0);
        gl_lds16(Bh + rb1 + k0, lds + OBH + l1);
        gl_lds16(Bl + rb0 + k0, lds + OBL + l0);
        gl_lds16(Bl + rb1 + k0, lds + OBL + l1);
        __syncthreads();
        short8 a_h[4], b_h[4], b_l[4];
        short8 a_l[(NT == 3) ? 4 : 1];
#pragma unroll
        for (int t = 0; t < 4; t++) {
            int ro = (wm + t * 16 + lm) * 32 + qx * 8;
            a_h[t] = *(const short8*)(lds + ro);
            if (NT == 3) a_l[t] = *(const short8*)(lds + OAL + ro);
        }
#pragma unroll
        for (int t = 0; t < 4; t++) {
            int ro = (wn + t * 16 + lm) * 32 + qx * 8;
            b_h[t] = *(const short8*)(lds + OBH + ro);
            b_l[t] = *(const short8*)(lds + OBL + ro);
        }
#pragma unroll
        for (int i = 0; i < 4; i++)
#pragma unroll
            for (int j = 0; j < 4; j++) {
                acc[i][j] = __builtin_amdgcn_mfma_f32_16x16x32_bf16(a_h[i], b_h[j], acc[i][j], 0, 0, 0);
                if (NT == 3)
                    acc[i][j] = __builtin_amdgcn_mfma_f32_16x16x32_bf16(a_l[i], b_h[j], acc[i][j], 0, 0, 0);
                acc[i][j] = __builtin_amdgcn_mfma_f32_16x16x32_bf16(a_h[i], b_l[j], acc[i][j], 0, 0, 0);
            }
        __syncthreads();
    }

    float mult = 1.f;
    if (MODE == 1) mult = fmaxf(scal[4] / 127.f, 1e-8f);
    float amax = 0.f;
#pragma unroll
    for (int i = 0; i < 4; i++)
#pragma unroll
        for (int j = 0; j < 4; j++)
#pragma unroll
            for (int r = 0; r < 4; r++) {
                float v = acc[i][j][r] * mult;
                amax = fmaxf(amax, fabsf(v));
                size_t row = (size_t)(bm + wm + i * 16 + quad * 4 + r);
                size_t col = (size_t)(bn + wn + j * 16 + lm);
                C[row * (size_t)N + col] = v;
            }
#pragma unroll
    for (int off = 32; off > 0; off >>= 1) amax = fmaxf(amax, __shfl_down(amax, off));
    if (lane == 0) wred[wave] = amax;
    __syncthreads();
    if (tid == 0) {
        float m = fmaxf(fmaxf(wred[0], wred[1]), fmaxf(wred[2], wred[3]));
        int slot = (MODE == 0) ? ((bn < 4096) ? 0 : ((bn < 5120) ? 1 : 2)) : 5;
        atomicMax((unsigned int*)(scal + slot), __float_as_uint(m));
    }
}

// ---------------- quantize q/k/v + RoPE on q/k ----------------
__global__ void quant_rope_hilo_kernel(const float* __restrict__ qkv,
                                       unsigned short* __restrict__ Qh,
                                       unsigned short* __restrict__ Ql,
                                       unsigned short* __restrict__ Kh,
                                       unsigned short* __restrict__ Kl,
                                       unsigned short* __restrict__ Vc,
                                       const float* __restrict__ scal)
{
    int t = blockIdx.x * 256 + threadIdx.x;
    int f = t * 8;
    int r = f / DD;
    int c = f - r * DD;
    int b = r >> 10, sp = r & 1023;
    const float* src = qkv + (size_t)r * DD + c;
    float x[8] __attribute__((aligned(16)));
    *(float4*)(x)     = *(const float4*)(src);
    *(float4*)(x + 4) = *(const float4*)(src + 4);

    if (c < 5120) {  // q or k: quantize then rope, split hi/lo
        float s; int d; unsigned short *dh, *dl;
        if (c < 4096) {
            s = fmaxf(scal[0] / 127.f, 1e-8f);
            int head = c >> 7; d = c & 127;
            size_t off = (((size_t)(b * NH + head) * SS + sp) << 7) + d;
            dh = Qh + off; dl = Ql + off;
        } else {
            int cc = c - 4096;
            s = fmaxf(scal[1] / 127.f, 1e-8f);
            int head = cc >> 7; d = cc & 127;
            size_t off = (((size_t)(b * NKV + head) * SS + sp) << 7) + d;
            dh = Kh + off; dl = Kl + off;
        }
        int cp = (d < 64) ? (c + 64) : (c - 64);
        float sgn = (d < 64) ? -1.f : 1.f;
        const float* psrc = qkv + (size_t)r * DD + cp;
        float p[8] __attribute__((aligned(16)));
        *(float4*)(p)     = *(const float4*)(psrc);
        *(float4*)(p + 4) = *(const float4*)(psrc + 4);
        unsigned short h8[8] __attribute__((aligned(16)));
        unsigned short l8[8] __attribute__((aligned(16)));
#pragma unroll
        for (int i = 0; i < 8; i++) {
            float xq = fqs(x[i], s);
            float pq = fqs(p[i], s);
            int fi = (d + i) & 63;
            float inv = expf((float)fi * -0.14391156831212787f);  // 10000^(-fi/64)
            float ang = (float)sp * inv;
            float sn, cs;
            sincosf(ang, &sn, &cs);
            float o = xq * cs + sgn * pq * sn;
            unsigned short hb = f2b(o);
            h8[i] = hb;
            l8[i] = f2b(o - b2f(hb));
        }
        *(uint4*)(dh) = *(uint4*)h8;
        *(uint4*)(dl) = *(uint4*)l8;
    } else {        // v: integer codes only (exact in bf16)
        int cc = c - 5120;
        float s = fmaxf(scal[2] / 127.f, 1e-8f);
        int head = cc >> 7, d = cc & 127;
        unsigned short* dst = Vc + (((size_t)(b * NKV + head) * SS + sp) << 7) + d;
        unsigned short o8[8] __attribute__((aligned(16)));
#pragma unroll
        for (int i = 0; i < 8; i++) {
            float code = fminf(fmaxf(rintf(x[i] / s), -127.f), 127.f);
            o8[i] = f2b(code);
        }
        *(uint4*)(dst) = *(uint4*)o8;
    }
}

// ---------------- transpose V codes: Vc[bh][key][d] -> Vt[bh][d][key] ----------------
__global__ void vtrans_kernel(const unsigned short* __restrict__ Vc,
                              unsigned short* __restrict__ Vt)
{
    __shared__ __attribute__((aligned(16))) unsigned short L[64][72];
    const int dtile = blockIdx.x;   // 0..1
    const int ktile = blockIdx.y;   // 0..15
    const int bh    = blockIdx.z;   // 0..15
    const int tid = threadIdx.x;
#pragma unroll
    for (int it = 0; it < 2; it++) {
        int lin = it * 256 + tid;
        int row = lin >> 3, c8 = (lin & 7) * 8;
        *(uint4*)&L[row][c8] =
            *(const uint4*)(Vc + ((size_t)bh * SS + ktile * 64 + row) * HD + dtile * 64 + c8);
    }
    __syncthreads();
#pragma unroll
    for (int it = 0; it < 2; it++) {
        int lin = it * 256 + tid;
        int dr = lin >> 3, k8 = (lin & 7) * 8;
        unsigned short o8[8] __attribute__((aligned(16)));
#pragma unroll
        for (int i = 0; i < 8; i++) o8[i] = L[k8 + i][dr];
        *(uint4*)(Vt + ((size_t)bh * HD + dtile * 64 + dr) * SS + ktile * 64 + k8) = *(uint4*)o8;
    }
}

// ---------------- attention pass 0: hi/lo QK^T, amax of clipped attn, cache raw scores ----------------
// Scores packed causally: per head hg, per q-chunk qc, tiles kt=0..qc of 64x64 f32.
// tile_base = (hg*136 + qc*(qc+1)/2 + kt) * 4096 ; element = qrow_local*64 + kcol_local.
__global__ __launch_bounds__(256, 2)
void attn_score_kernel(const unsigned short* __restrict__ Qh,
                       const unsigned short* __restrict__ Ql,
                       const unsigned short* __restrict__ Kh,
                       const unsigned short* __restrict__ Kl,
                       float* __restrict__ Scr,
                       float* __restrict__ scal)
{
    __shared__ float wred[4];
    const int x = blockIdx.x;
    const int qc = 15 - (x & 15);          // heavy blocks first
    const int h = (x >> 4) & 31, b = x >> 9;
    const int hk = h >> 2;
    const int tid = threadIdx.x;
    const int wave = tid >> 6, lane = tid & 63;
    const int lm = lane & 15, quad = lane >> 4;
    const float coef = scal[7] * SCALE;

    const size_t qbase = ((size_t)((b * NH + h) * SS) + qc * 64 + wave * 16 + lm) * HD + quad * 8;
    short8 qh[4], ql[4];
#pragma unroll
    for (int kk = 0; kk < 4; kk++) {
        qh[kk] = *(const short8*)(Qh + qbase + kk * 32);
        ql[kk] = *(const short8*)(Ql + qbase + kk * 32);
    }
    const size_t kbase = (size_t)((b * NKV + hk) * SS) * HD + quad * 8;
    const size_t scrbase = ((size_t)(b * NH + h) * 136 + (size_t)(qc * (qc + 1) / 2)) * 4096;

    const f4 z = {0.f, 0.f, 0.f, 0.f};
    float amax = 0.f;
    const int qg = qc * 64 + wave * 16 + quad * 4;

    for (int kt = 0; kt <= qc; kt++) {
        f4 acc[4];
#pragma unroll
        for (int j = 0; j < 4; j++) acc[j] = z;
        __builtin_amdgcn_s_setprio(1);
#pragma unroll
        for (int j = 0; j < 4; j++) {
            const size_t kb = kbase + (size_t)(kt * 64 + j * 16 + lm) * HD;
#pragma unroll
            for (int kk = 0; kk < 4; kk++) {
                short8 kh8 = *(const short8*)(Kh + kb + kk * 32);
                short8 kl8 = *(const short8*)(Kl + kb + kk * 32);
                acc[j] = __builtin_amdgcn_mfma_f32_16x16x32_bf16(qh[kk], kh8, acc[j], 0, 0, 0);
                acc[j] = __builtin_amdgcn_mfma_f32_16x16x32_bf16(ql[kk], kh8, acc[j], 0, 0, 0);
                acc[j] = __builtin_amdgcn_mfma_f32_16x16x32_bf16(qh[kk], kl8, acc[j], 0, 0, 0);
            }
        }
        __builtin_amdgcn_s_setprio(0);
        const bool diag = (kt == qc);
        float* st = Scr + scrbase + (size_t)kt * 4096;
#pragma unroll
        for (int j = 0; j < 4; j++) {
            int kg = kt * 64 + j * 16 + lm;
#pragma unroll
            for (int r = 0; r < 4; r++) {
                float sv = acc[j][r];
                st[(wave * 16 + quad * 4 + r) * 64 + j * 16 + lm] = sv;
                bool ok = (!diag) || (kg <= qg + r);
                if (ok) {
                    float a = 0.5f + coef * sv;
                    a = fminf(fmaxf(a, 0.f), 1.f);
                    amax = fmaxf(amax, a);
                }
            }
        }
    }

#pragma unroll
    for (int off = 32; off > 0; off >>= 1) amax = fmaxf(amax, __shfl_down(amax, off));
    if (lane == 0) wred[wave] = amax;
    __syncthreads();
    if (tid == 0) {
        float m = fmaxf(fmaxf(wred[0], wred[1]), fmaxf(wred[2], wred[3]));
        atomicMax((unsigned int*)(scal + 3), __float_as_uint(m));
    }
}

// ---------------- attention pass 1: read scores, quantize, PV on codes ----------------
// Scores are read back directly in the PV A-fragment layout (row=lm, k=quad*8..):
// no recompute, no Q/K loads, no LDS P-staging.
__global__ __launch_bounds__(256, 4)
void attn_pv_kernel(const float* __restrict__ Scr,
                    const unsigned short* __restrict__ Vt,
                    float* __restrict__ O,
                    float* __restrict__ scal)
{
    __shared__ float wred[4];
    const int x = blockIdx.x;
    const int qc = 15 - (x & 15);          // heavy blocks first
    const int h = (x >> 4) & 31, b = x >> 9;
    const int hk = h >> 2;
    const int tid = threadIdx.x;
    const int wave = tid >> 6, lane = tid & 63;
    const int lm = lane & 15, quad = lane >> 4;
    const float coef = scal[7] * SCALE;
    const float s_a = fmaxf(scal[3] / 255.f, 1e-8f);
    const float s_v = fmaxf(scal[2] / 127.f, 1e-8f);
    const float s_av = s_a * s_v;

    const size_t vbase = (size_t)((b * NKV + hk) * HD) * SS + quad * 8;
    const size_t scrbase = ((size_t)(b * NH + h) * 136 + (size_t)(qc * (qc + 1) / 2)) * 4096
                         + (size_t)(wave * 16 + lm) * 64 + quad * 8;
    const int qg = qc * 64 + wave * 16 + lm;   // this lane's q-row (A-frag row)

    const f4 z = {0.f, 0.f, 0.f, 0.f};
    f4 oacc[8];
#pragma unroll
    for (int j2 = 0; j2 < 8; j2++) oacc[j2] = z;

    for (int kt = 0; kt <= qc; kt++) {
        const float* sp = Scr + scrbase + (size_t)kt * 4096;
        float sc[16] __attribute__((aligned(16)));
        *(float4*)(sc)      = *(const float4*)(sp);
        *(float4*)(sc + 4)  = *(const float4*)(sp + 4);
        *(float4*)(sc + 8)  = *(const float4*)(sp + 32);
        *(float4*)(sc + 12) = *(const float4*)(sp + 36);
        const bool diag = (kt == qc);
        unsigned short cd[16] __attribute__((aligned(16)));
#pragma unroll
        for (int i = 0; i < 8; i++) {
            int kg = kt * 64 + quad * 8 + i;
            bool ok = (!diag) || (kg <= qg);
            float a = 0.5f + coef * sc[i];
            a = fminf(fmaxf(a, 0.f), 1.f);
            cd[i] = f2b(ok ? fminf(rintf(a / s_a), 255.f) : 0.f);
        }
#pragma unroll
        for (int i = 0; i < 8; i++) {
            int kg = kt * 64 + 32 + quad * 8 + i;
            bool ok = (!diag) || (kg <= qg);
            float a = 0.5f + coef * sc[8 + i];
            a = fminf(fmaxf(a, 0.f), 1.f);
            cd[8 + i] = f2b(ok ? fminf(rintf(a / s_a), 255.f) : 0.f);
        }
        short8 pa0 = *(const short8*)(cd);
        short8 pa1 = *(const short8*)(cd + 8);
        __builtin_amdgcn_s_setprio(1);
#pragma unroll
        for (int j2 = 0; j2 < 8; j2++) {
            const unsigned short* vp = Vt + vbase + (size_t)(j2 * 16 + lm) * SS + kt * 64;
            short8 v0 = *(const short8*)(vp);
            short8 v1 = *(const short8*)(vp + 32);
            oacc[j2] = __builtin_amdgcn_mfma_f32_16x16x32_bf16(pa0, v0, oacc[j2], 0, 0, 0);
            oacc[j2] = __builtin_amdgcn_mfma_f32_16x16x32_bf16(pa1, v1, oacc[j2], 0, 0, 0);
        }
        __builtin_amdgcn_s_setprio(0);
    }

    float am = 0.f;
    const size_t orow = (size_t)(b * SS + qc * 64 + wave * 16 + quad * 4);
#pragma unroll
    for (int j2 = 0; j2 < 8; j2++)
#pragma unroll
        for (int r = 0; r < 4; r++) {
            float v = oacc[j2][r] * s_av;
            am = fmaxf(am, fabsf(v));
            O[(orow + r) * DQ + h * HD + j2 * 16 + lm] = v;
        }
#pragma unroll
    for (int off = 32; off > 0; off >>= 1) am = fmaxf(am, __shfl_down(am, off));
    if (lane == 0) wred[wave] = am;
    __syncthreads();
    if (tid == 0) {
        float m = fmaxf(fmaxf(wred[0], wred[1]), fmaxf(wred[2], wred[3]));
        atomicMax((unsigned int*)(scal + 4), __float_as_uint(m));
    }
}

// ---------------- quantize O -> integer codes (bf16-exact) for GEMM2 ----------------
__global__ void quant_o_codes_kernel(const float* __restrict__ O,
                                     const float* __restrict__ scal,
                                     unsigned short* __restrict__ Oq)
{
    size_t t = (size_t)blockIdx.x * 256 + threadIdx.x;
    float s = fmaxf(scal[4] / 127.f, 1e-8f);
    float4 v = *(const float4*)(O + t * 4);
    unsigned short o[4] __attribute__((aligned(8)));
    o[0] = f2b(fminf(fmaxf(rintf(v.x / s), -127.f), 127.f));
    o[1] = f2b(fminf(fmaxf(rintf(v.y / s), -127.f), 127.f));
    o[2] = f2b(fminf(fmaxf(rintf(v.z / s), -127.f), 127.f));
    o[3] = f2b(fminf(fmaxf(rintf(v.w / s), -127.f), 127.f));
    *(uint2*)(Oq + t * 4) = *(uint2*)o;
}

// ---------------- final quantize -> f32 output ----------------
__global__ void final_q_kernel(const float* __restrict__ X,
                               const float* __restrict__ scal,
                               float* __restrict__ out)
{
    size_t t = (size_t)blockIdx.x * 256 + threadIdx.x;
    float s = fmaxf(scal[5] / 127.f, 1e-8f);
    float4 v = *(const float4*)(X + t * 4);
    float4 o;
    o.x = fqs(v.x, s);
    o.y = fqs(v.y, s);
    o.z = fqs(v.z, s);
    o.w = fqs(v.w, s);
    *(float4*)(out + t * 4) = o;
}

// ---------------- launch ----------------
extern "C" void kernel_launch(void* const* d_in, const int* in_sizes, int n_in,
                              void* d_out, int out_size, void* d_ws, size_t ws_size,
                              hipStream_t stream)
{
    const unsigned short* x      = (const unsigned short*)d_in[0];
    const unsigned short* w_qkv  = (const unsigned short*)d_in[1];
    const unsigned short* w_o    = (const unsigned short*)d_in[2];
    const unsigned short* slope  = (const unsigned short*)d_in[3];
    (void)in_sizes; (void)n_in; (void)out_size; (void)ws_size;

    char* ws = (char*)d_ws;
    float* scal          = (float*)ws;                         // slots 0..7 (256 B reserved)
    unsigned short* xh   = (unsigned short*)(ws + 256);        // 12.58M bf16
    unsigned short* xl   = (unsigned short*)(ws + 25166080);
    unsigned short* wqh  = (unsigned short*)(ws + 50331904);   // 37.75M bf16
    unsigned short* wql  = (unsigned short*)(ws + 125829376);
    float* qkv           = (float*)(ws + 201326848);           // 2048*6144 f32 (dead after rope)
    // attention buffers (inside the old Qf/Kf/Vf f32 footprint, ends 301990144):
    unsigned short* Qh   = (unsigned short*)(ws + 251658496);  // 16.78MB
    unsigned short* Ql   = (unsigned short*)(ws + 268435712);  // 16.78MB
    unsigned short* Kh   = (unsigned short*)(ws + 285212928);  // 4.19MB
    unsigned short* Kl   = (unsigned short*)(ws + 289407232);  // 4.19MB
    unsigned short* Vt   = (unsigned short*)(ws + 293601536);  // 4.19MB [bh][d][key]
    unsigned short* Vc   = (unsigned short*)(ws + 297795840);  // 4.19MB [bh][key][d] (ends 301990144)
    // regions dead after GEMM1 (xh/xl/wqh/wql) and after rope (qkv) are reused:
    unsigned short* woh  = (unsigned short*)(ws + 256);        // 16.78M bf16 (in xh/xl)
    unsigned short* wol  = (unsigned short*)(ws + 33554688);   // (xl tail + wqh head)
    float* O             = (float*)(ws + 67109376);            // 2048*4096 f32 (in wqh)
    float* Scr           = (float*)(ws + 100663808);           // 142.6M scores (dies before Oqc/out2 written)
    unsigned short* Oqc  = (unsigned short*)(ws + 100663808);  // codes bf16 [ends 134218240] (after pass 1)
    float* out2          = (float*)(ws + 201326848);           // 2048*4096 f32 (in dead qkv)
    float* outp          = (float*)d_out;                      // OUTPUT IS FLOAT32

    hipMemsetAsync(scal, 0, 256, stream);
    detect_kernel<<<1, 256, 0, stream>>>(x, scal);
    slope_kernel<<<1, 64, 0, stream>>>(slope, scal);
    convert_split_kernel<<<6144, 256, 0, stream>>>(x, xh, xl, scal);
    convert_split_kernel<<<18432, 256, 0, stream>>>(w_qkv, wqh, wql, scal);
    gemm_hilo_kernel<3, 0><<<dim3(48, 16), 256, 0, stream>>>(xh, xl, wqh, wql, qkv,
                                                             MM, DD, DD, scal);
    quant_rope_hilo_kernel<<<6144, 256, 0, stream>>>(qkv, Qh, Ql, Kh, Kl, Vc, scal);
    vtrans_kernel<<<dim3(2, 16, 16), 256, 0, stream>>>(Vc, Vt);
    convert_split_kernel<<<8192, 256, 0, stream>>>(w_o, woh, wol, scal);  // after GEMM1 (aliased)
    attn_score_kernel<<<1024, 256, 0, stream>>>(Qh, Ql, Kh, Kl, Scr, scal);
    attn_pv_kernel<<<1024, 256, 0, stream>>>(Scr, Vt, O, scal);
    quant_o_codes_kernel<<<8192, 256, 0, stream>>>(O, scal, Oqc);
    gemm_hilo_kernel<2, 1><<<dim3(32, 16), 256, 0, stream>>>(Oqc, Oqc, woh, wol, out2,
                                                             MM, DQ, DQ, scal);
    final_q_kernel<<<8192, 256, 0, stream>>>(out2, scal, outp);
}